// Round 9
// baseline (1282.540 us; speedup 1.0000x reference)
//
#include <hip/hip_runtime.h>

#define TT     32
#define HW     4096           // 64*64
#define LROW   68             // 66 cols + 2 pad -> rows 16B-aligned (b128 reads)
#define LPLANE (6 * LROW)     // 6 halo rows per cin = 408
#define SXSZ   (3 * LPLANE)   // 1224 floats per plane buffer
#define NSTG   (3 * 6 * 66)   // 1188 staged elements per plane

__device__ __forceinline__ float fsigmoid(float x) {
    return __builtin_amdgcn_rcpf(1.0f + __builtin_amdgcn_exp2f(x * -1.4426950408889634f));
}
__device__ __forceinline__ float ftanh(float x) {
    return 2.0f * __builtin_amdgcn_rcpf(1.0f + __builtin_amdgcn_exp2f(x * -2.8853900817779268f)) - 1.0f;
}
// force a wave-uniform float into an SGPR
__device__ __forceinline__ float sgprf(float v) {
    return __uint_as_float(__builtin_amdgcn_readfirstlane(__float_as_uint(v)));
}

// (256,2): round 0 proved this tier allocates >64 VGPRs cleanly. Round 8
// showed the residual spill is SCHEDULER-induced (full unroll clusters all
// 90 LDS loads -> ~300 transient live floats); sched_barrier(0) per (ci,kh)
// group bounds the scheduling window so peak pressure ~110 regs.
__global__ __launch_bounds__(256, 2) void convqrnn(
    const float* __restrict__ X,    // (4,3,32,64,64)
    const float* __restrict__ Wc,   // (256,3,2,3,3)
    const float* __restrict__ bc,   // (256)
    const float* __restrict__ Wci,  // (64,64,64)
    const float* __restrict__ Wcf,
    const float* __restrict__ Wco,
    float* __restrict__ out)        // (4,64,32,64,64)
{
    __shared__ float sx[2 * SXSZ];   // double-buffered staged plane (9792 B)
    __shared__ float wl[1152];       // weights: ((cl*4+g)*9 + ci*3+kh)*8 + dt*3 + kw

    const int tid = threadIdx.x;
    const int h0  = blockIdx.x * 4;    // 16 row-tiles of height 4, full width
    const int co0 = blockIdx.y * 4;    // this block handles couts co0..co0+3
    const int b   = blockIdx.z;

    // wave cl owns cout co0+cl, ALL 4 gates, for its lane's 4-col strip
    const int cl = tid >> 6;           // wave-uniform cout-local
    const int co = co0 + cl;
    const int l  = tid & 63;
    const int r  = l >> 4;             // 0..3 tile row
    const int c0 = (l & 15) * 4;       // col base (0,4,...,60)

    // peephole params for this thread's 4 pixels: contiguous -> float4
    const int pbase = co * HW + (h0 + r) * 64 + c0;
    float wciA[4], wcfA[4], wcoA[4];
    *(float4*)wciA = *(const float4*)&Wci[pbase];
    *(float4*)wcfA = *(const float4*)&Wcf[pbase];
    *(float4*)wcoA = *(const float4*)&Wco[pbase];

    // ---- cooperative fill of the LDS weight table (864 elements) ----
    // Wc[(g*64+co)*54 + ci*18 + dt*9 + kh*3 + kw]
    for (int fi = tid; fi < 864; fi += 256) {
        int cl2 = fi / 216;            // 216 = 4 gates * 54
        int r1  = fi - cl2 * 216;
        int g2  = r1 / 54;
        int r2  = r1 - g2 * 54;
        int ci  = r2 / 18;
        int r3  = r2 - ci * 18;
        int kh  = r3 / 6;
        int r4  = r3 - kh * 6;
        int dt  = r4 / 3;
        int kw  = r4 - dt * 3;
        wl[((cl2 * 4 + g2) * 9 + ci * 3 + kh) * 8 + dt * 3 + kw] =
            Wc[(size_t)(g2 * 64 + co0 + cl2) * 54 + ci * 18 + dt * 9 + kh * 3 + kw];
    }
    // biases for this wave's cout, all 4 gates -> SGPRs
    float bg0 = sgprf(bc[0 * 64 + co]);
    float bg1 = sgprf(bc[1 * 64 + co]);
    float bg2 = sgprf(bc[2 * 64 + co]);
    float bg3 = sgprf(bc[3 * 64 + co]);

    // ---- staging precompute: 5 chunks of 256 covering 3x6x66 halo tile ----
    const float* __restrict__ Xb = X + (size_t)b * (3 * TT * HW);
    int soff[5];
    int goff[5];
    int svmask = 0;
    #pragma unroll
    for (int k = 0; k < 5; ++k) {
        int idx  = tid + k * 256;
        bool inr = (idx < NSTG);
        int idc  = inr ? idx : 0;
        int ci   = idc / 396;              // 6*66
        int rem  = idc - ci * 396;
        int y    = rem / 66;
        int x    = rem - y * 66;
        int gh   = h0 + y - 1;
        int gw   = x - 1;
        bool v   = inr && (gh >= 0) && (gh < 64) && (gw >= 0) && (gw < 64);
        int ghc  = gh < 0 ? 0 : (gh > 63 ? 63 : gh);
        int gwc  = gw < 0 ? 0 : (gw > 63 ? 63 : gw);
        soff[k]  = inr ? (ci * LPLANE + y * LROW + x) : (LROW - 1); // dummy pad slot
        goff[k]  = ci * (TT * HW) + ghc * 64 + gwc;                 // plane 0
        svmask  |= (v ? 1 : 0) << k;
    }

    // prologue: stage plane t=0 into buffer 0
    #pragma unroll
    for (int k = 0; k < 5; ++k) {
        float v = ((svmask >> k) & 1) ? Xb[goff[k]] : 0.0f;
        sx[soff[k]] = v;
        goff[k] += HW;                       // -> plane 1
    }

    // output: this thread's 4 pixels are contiguous -> float4 stores
    float* __restrict__ outw =
        out + (size_t)(b * 64 + co) * (TT * HW) + (h0 + r) * 64 + c0;
    int ooff = 0;

    // nv = dt0 sums of current plane (becomes next step's carry); C = cell state
    float nv[4][4];
    #pragma unroll
    for (int g2 = 0; g2 < 4; ++g2)
        #pragma unroll
        for (int j = 0; j < 4; ++j) nv[g2][j] = 0.0f;
    float C0 = 0.f, C1 = 0.f, C2 = 0.f, C3 = 0.f;

    __syncthreads();   // plane 0 staged + weight table filled

    for (int t = 0; t < TT; ++t) {
        // never-taken uniform MayDef on wl: keeps LICM from hoisting the
        // weight loads into ~400 registers. grid.x==16 -> never executes.
        if (blockIdx.x == 0xFFFFFFFFu) wl[tid] = 0.0f;

        const float* __restrict__ sxb = &sx[(t & 1) * SXSZ];

        // s init = bias + carry (dt0 taps of plane t-1); reset n accumulators
        float sv[4][4];
        #pragma unroll
        for (int j = 0; j < 4; ++j) {
            sv[0][j] = bg0 + nv[0][j];  nv[0][j] = 0.f;
            sv[1][j] = bg1 + nv[1][j];  nv[1][j] = 0.f;
            sv[2][j] = bg2 + nv[2][j];  nv[2][j] = 0.f;
            sv[3][j] = bg3 + nv[3][j];  nv[3][j] = 0.f;
        }

        // prefetch next plane's staging values (VMEM overlaps FMAs)
        float stv[5];
        if (t < TT - 1) {                    // uniform branch
            #pragma unroll
            for (int k = 0; k < 5; ++k) {
                stv[k] = ((svmask >> k) & 1) ? Xb[goff[k]] : 0.0f;
                goff[k] += HW;
            }
        }

        // conv: all 4 gates, this wave's cout; window shared across gates.
        // sched_barrier(0) per (ci,kh) group bounds the scheduler's
        // load-clustering window -> no spill (round-8 lesson).
        #pragma unroll
        for (int ci = 0; ci < 3; ++ci)
            #pragma unroll
            for (int kh = 0; kh < 3; ++kh) {
                // window row: 6 floats (b128 + b64, 2-way banked = free)
                const float* rowp = &sxb[ci * LPLANE + (r + kh) * LROW + c0];
                float4 lo = *(const float4*)rowp;
                float2 hi = *(const float2*)(rowp + 4);
                const float w0 = lo.x, w1 = lo.y, w2 = lo.z;
                const float w3 = lo.w, w4 = hi.x, w5 = hi.y;

                #pragma unroll
                for (int g2 = 0; g2 < 4; ++g2) {
                    // uniform-address b128 broadcasts; q0={p0,p1,p2,c0}, q1={c1,c2,pad,pad}
                    const int wb = ((cl * 4 + g2) * 9 + ci * 3 + kh) * 8;
                    float4 q0 = *(const float4*)&wl[wb];
                    float4 q1 = *(const float4*)&wl[wb + 4];

                    sv[g2][0] += q0.w * w0;  sv[g2][1] += q0.w * w1;
                    sv[g2][2] += q0.w * w2;  sv[g2][3] += q0.w * w3;
                    sv[g2][0] += q1.x * w1;  sv[g2][1] += q1.x * w2;
                    sv[g2][2] += q1.x * w3;  sv[g2][3] += q1.x * w4;
                    sv[g2][0] += q1.y * w2;  sv[g2][1] += q1.y * w3;
                    sv[g2][2] += q1.y * w4;  sv[g2][3] += q1.y * w5;

                    nv[g2][0] += q0.x * w0;  nv[g2][1] += q0.x * w1;
                    nv[g2][2] += q0.x * w2;  nv[g2][3] += q0.x * w3;
                    nv[g2][0] += q0.y * w1;  nv[g2][1] += q0.y * w2;
                    nv[g2][2] += q0.y * w3;  nv[g2][3] += q0.y * w4;
                    nv[g2][0] += q0.z * w2;  nv[g2][1] += q0.z * w3;
                    nv[g2][2] += q0.z * w4;  nv[g2][3] += q0.z * w5;
                }

                __builtin_amdgcn_sched_barrier(0);
            }

        // commit staged plane t+1 (other buffer; readers of it finished at t-1)
        if (t < TT - 1) {                    // uniform branch
            float* __restrict__ sxn = &sx[((t + 1) & 1) * SXSZ];
            #pragma unroll
            for (int k = 0; k < 5; ++k) sxn[soff[k]] = stv[k];
        }

        // recurrence: fully thread-local (no exchange, no barrier needed)
        float o0, o1, o2, o3;
        {
            const float ig = fsigmoid(sv[0][0] + wciA[0] * C0);
            const float fg = fsigmoid(sv[1][0] + wcfA[0] * C0);
            const float Cn = fg * C0 + ig * ftanh(sv[2][0]);
            const float og = fsigmoid(sv[3][0] + wcoA[0] * Cn);
            o0 = og * ftanh(Cn);  C0 = Cn;
        }
        {
            const float ig = fsigmoid(sv[0][1] + wciA[1] * C1);
            const float fg = fsigmoid(sv[1][1] + wcfA[1] * C1);
            const float Cn = fg * C1 + ig * ftanh(sv[2][1]);
            const float og = fsigmoid(sv[3][1] + wcoA[1] * Cn);
            o1 = og * ftanh(Cn);  C1 = Cn;
        }
        {
            const float ig = fsigmoid(sv[0][2] + wciA[2] * C2);
            const float fg = fsigmoid(sv[1][2] + wcfA[2] * C2);
            const float Cn = fg * C2 + ig * ftanh(sv[2][2]);
            const float og = fsigmoid(sv[3][2] + wcoA[2] * Cn);
            o2 = og * ftanh(Cn);  C2 = Cn;
        }
        {
            const float ig = fsigmoid(sv[0][3] + wciA[3] * C3);
            const float fg = fsigmoid(sv[1][3] + wcfA[3] * C3);
            const float Cn = fg * C3 + ig * ftanh(sv[2][3]);
            const float og = fsigmoid(sv[3][3] + wcoA[3] * Cn);
            o3 = og * ftanh(Cn);  C3 = Cn;
        }
        *(float4*)&outw[ooff] = make_float4(o0, o1, o2, o3);
        ooff += HW;

        __syncthreads();   // staged plane t+1 visible; sx[t&1] reads done
    }
}

extern "C" void kernel_launch(void* const* d_in, const int* in_sizes, int n_in,
                              void* d_out, int out_size, void* d_ws, size_t ws_size,
                              hipStream_t stream) {
    const float* X   = (const float*)d_in[0];
    const float* Wc  = (const float*)d_in[1];
    const float* bc  = (const float*)d_in[2];
    const float* Wci = (const float*)d_in[3];
    const float* Wcf = (const float*)d_in[4];
    const float* Wco = (const float*)d_in[5];
    float* out = (float*)d_out;

    dim3 grid(16, 16, 4);   // row-tiles, cout-quads, batch
    convqrnn<<<grid, 256, 0, stream>>>(X, Wc, bc, Wci, Wcf, Wco, out);
}

// Round 11
// 450.438 us; speedup vs baseline: 2.8473x; 2.8473x over previous
//
#include <hip/hip_runtime.h>

#define TT     32
#define HW     4096            // 64*64
#define LROW   68              // 66 cols + 2 pad -> rows 16B-aligned
#define NROWS  10              // 8 output rows + 2 halo
#define LPLANE (NROWS * LROW)  // 680
#define SXSZ   (3 * LPLANE)    // 2040 floats per plane buffer
#define NSTG   (3 * NROWS * 66) // 1980 staged elements per plane
#define GBSZ   4096            // 2 couts * 4 gates * 512 px

__device__ __forceinline__ float fsigmoid(float x) {
    return __builtin_amdgcn_rcpf(1.0f + __builtin_amdgcn_exp2f(x * -1.4426950408889634f));
}
__device__ __forceinline__ float ftanh(float x) {
    return 2.0f * __builtin_amdgcn_rcpf(1.0f + __builtin_amdgcn_exp2f(x * -2.8853900817779268f)) - 1.0f;
}
__device__ __forceinline__ float sgprf(float v) {
    return __uint_as_float(__builtin_amdgcn_readfirstlane(__float_as_uint(v)));
}

// 8 waves = 4 gates x 2 couts; thread owns 2 rows x 4 cols. Spill-proof
// ingredients only: named scalar accumulators, <=54 SGPR weights per wave.
__global__ __launch_bounds__(512, 2) void convqrnn(
    const float* __restrict__ X,    // (4,3,32,64,64)
    const float* __restrict__ Wc,   // (256,3,2,3,3)
    const float* __restrict__ bc,   // (256)
    const float* __restrict__ Wci,  // (64,64,64)
    const float* __restrict__ Wcf,
    const float* __restrict__ Wco,
    float* __restrict__ out)        // (4,64,32,64,64)
{
    __shared__ float sx[2 * SXSZ];  // 16320 B staged planes (double-buffered)
    __shared__ float gb[2 * GBSZ];  // 32768 B gate exchange (double-buffered)

    const int tid = threadIdx.x;
    const int h0  = blockIdx.x * 8;    // 8 row-tiles of height 8
    const int co0 = blockIdx.y * 2;    // couts {co0, co0+1}
    const int b   = blockIdx.z;

    // gate-compute mapping: wave = (gate g, cout-local cA)
    const int w  = tid >> 6;
    const int g  = w >> 1;
    const int cA = w & 1;
    const int co = co0 + cA;
    const int l  = tid & 63;
    const int r2 = l >> 4;             // row-pair 0..3 -> rows 2r2, 2r2+1
    const int c0 = (l & 15) * 4;       // col base

    // conv weights for (g, co): 54 floats -> SGPRs (proven no-spill pattern)
    float wgt[54];
    {
        const float* __restrict__ wrow = Wc + (size_t)(g * 64 + co) * 54;
        #pragma unroll
        for (int j = 0; j < 54; ++j) wgt[j] = sgprf(wrow[j]);
    }
    const float bg = sgprf(bc[g * 64 + co]);

    // recurrence-owner mapping: thread owns 2 consecutive px of one cout
    const int cow = tid >> 8;           // 0..1
    const int p2  = (tid & 255) * 2;    // pixel pair within 8x64 tile
    const int ppix = (co0 + cow) * HW + h0 * 64 + p2;
    const float2 pwci = *(const float2*)&Wci[ppix];
    const float2 pwcf = *(const float2*)&Wcf[ppix];
    const float2 pwco = *(const float2*)&Wco[ppix];
    float* __restrict__ outp =
        out + (size_t)(b * 64 + co0 + cow) * (TT * HW) + h0 * 64 + p2;

    // ---- staging precompute: 4 chunks of 512 covering 3x10x66 halo tile ----
    const float* __restrict__ Xb = X + (size_t)b * (3 * TT * HW);
    int soff[4];
    int goff[4];
    int svmask = 0;
    #pragma unroll
    for (int k = 0; k < 4; ++k) {
        int idx  = tid + k * 512;
        bool inr = (idx < NSTG);
        int idc  = inr ? idx : 0;
        int ci   = idc / 660;              // 10*66
        int rem  = idc - ci * 660;
        int y    = rem / 66;
        int x    = rem - y * 66;
        int gh   = h0 + y - 1;
        int gw   = x - 1;
        bool v   = inr && (gh >= 0) && (gh < 64) && (gw >= 0) && (gw < 64);
        int ghc  = gh < 0 ? 0 : (gh > 63 ? 63 : gh);
        int gwc  = gw < 0 ? 0 : (gw > 63 ? 63 : gw);
        soff[k]  = inr ? (ci * LPLANE + y * LROW + x) : 66;  // 66 = pad slot
        goff[k]  = ci * (TT * HW) + ghc * 64 + gwc;          // plane 0
        svmask  |= (v ? 1 : 0) << k;
    }

    // prologue: stage plane t=0 into buffer 0
    #pragma unroll
    for (int k = 0; k < 4; ++k) {
        float v = ((svmask >> k) & 1) ? Xb[goff[k]] : 0.0f;
        sx[soff[k]] = v;
        goff[k] += HW;
    }

    // dt0 carries (named scalars) and cell state
    float na0 = 0.f, na1 = 0.f, na2 = 0.f, na3 = 0.f;   // row 2r2
    float nb0 = 0.f, nb1 = 0.f, nb2 = 0.f, nb3 = 0.f;   // row 2r2+1
    float Cc0 = 0.f, Cc1 = 0.f;

    __syncthreads();   // plane 0 staged

    for (int t = 0; t < TT; ++t) {
        const float* __restrict__ sxb = &sx[(t & 1) * SXSZ];
        float*       __restrict__ gbb = &gb[(t & 1) * GBSZ];

        // s init = bias + carry; reset carries
        float sa0 = bg + na0, sa1 = bg + na1, sa2 = bg + na2, sa3 = bg + na3;
        float sb0 = bg + nb0, sb1 = bg + nb1, sb2 = bg + nb2, sb3 = bg + nb3;
        na0 = na1 = na2 = na3 = 0.f;
        nb0 = nb1 = nb2 = nb3 = 0.f;

        // prefetch next plane's staging values (VMEM overlaps FMAs)
        float stv[4];
        if (t < TT - 1) {                    // uniform branch
            #pragma unroll
            for (int k = 0; k < 4; ++k) {
                stv[k] = ((svmask >> k) & 1) ? Xb[goff[k]] : 0.0f;
                goff[k] += HW;
            }
        }

        // conv: per ci read 4 window rows ONCE (12 LDS ops), reuse across kh
        #pragma unroll
        for (int ci = 0; ci < 3; ++ci) {
            float wv[4][6];
            #pragma unroll
            for (int j = 0; j < 4; ++j) {
                const float* rowp = &sxb[ci * LPLANE + (2 * r2 + j) * LROW + c0];
                float4 lo = *(const float4*)rowp;       // 16B aligned
                float2 hi = *(const float2*)(rowp + 4);
                wv[j][0] = lo.x; wv[j][1] = lo.y; wv[j][2] = lo.z;
                wv[j][3] = lo.w; wv[j][4] = hi.x; wv[j][5] = hi.y;
            }
            #pragma unroll
            for (int kh = 0; kh < 3; ++kh)
                #pragma unroll
                for (int kw = 0; kw < 3; ++kw) {
                    const float wp = wgt[ci * 18 +     kh * 3 + kw];
                    const float wc = wgt[ci * 18 + 9 + kh * 3 + kw];
                    sa0 += wc * wv[kh    ][kw + 0];  sa1 += wc * wv[kh    ][kw + 1];
                    sa2 += wc * wv[kh    ][kw + 2];  sa3 += wc * wv[kh    ][kw + 3];
                    sb0 += wc * wv[kh + 1][kw + 0];  sb1 += wc * wv[kh + 1][kw + 1];
                    sb2 += wc * wv[kh + 1][kw + 2];  sb3 += wc * wv[kh + 1][kw + 3];
                    na0 += wp * wv[kh    ][kw + 0];  na1 += wp * wv[kh    ][kw + 1];
                    na2 += wp * wv[kh    ][kw + 2];  na3 += wp * wv[kh    ][kw + 3];
                    nb0 += wp * wv[kh + 1][kw + 0];  nb1 += wp * wv[kh + 1][kw + 1];
                    nb2 += wp * wv[kh + 1][kw + 2];  nb3 += wp * wv[kh + 1][kw + 3];
                }
        }

        // gate exchange: 2 b128 writes (both rows)
        const int gbase = (cA * 4 + g) * 512 + (2 * r2) * 64 + c0;
        *(float4*)&gbb[gbase]      = make_float4(sa0, sa1, sa2, sa3);
        *(float4*)&gbb[gbase + 64] = make_float4(sb0, sb1, sb2, sb3);

        // commit staged plane t+1 into the other buffer
        if (t < TT - 1) {                    // uniform branch
            float* __restrict__ sxn = &sx[((t + 1) & 1) * SXSZ];
            #pragma unroll
            for (int k = 0; k < 4; ++k) sxn[soff[k]] = stv[k];
        }

        __syncthreads();   // gates(t) + plane t+1 visible

        // recurrence: owner thread, 2 pixels of one cout (4x b64 gate reads)
        {
            const int rb = cow * 4 * 512 + p2;
            const float2 iv = *(const float2*)&gbb[rb];
            const float2 fv = *(const float2*)&gbb[rb + 512];
            const float2 gv = *(const float2*)&gbb[rb + 1024];
            const float2 ov = *(const float2*)&gbb[rb + 1536];
            float o0, o1;
            {
                const float ig = fsigmoid(iv.x + pwci.x * Cc0);
                const float fg = fsigmoid(fv.x + pwcf.x * Cc0);
                const float Cn = fg * Cc0 + ig * ftanh(gv.x);
                const float og = fsigmoid(ov.x + pwco.x * Cn);
                o0 = og * ftanh(Cn);  Cc0 = Cn;
            }
            {
                const float ig = fsigmoid(iv.y + pwci.y * Cc1);
                const float fg = fsigmoid(fv.y + pwcf.y * Cc1);
                const float Cn = fg * Cc1 + ig * ftanh(gv.y);
                const float og = fsigmoid(ov.y + pwco.y * Cn);
                o1 = og * ftanh(Cn);  Cc1 = Cn;
            }
            *(float2*)&outp[t * HW] = make_float2(o0, o1);
        }
    }
}

extern "C" void kernel_launch(void* const* d_in, const int* in_sizes, int n_in,
                              void* d_out, int out_size, void* d_ws, size_t ws_size,
                              hipStream_t stream) {
    const float* X   = (const float*)d_in[0];
    const float* Wc  = (const float*)d_in[1];
    const float* bc  = (const float*)d_in[2];
    const float* Wci = (const float*)d_in[3];
    const float* Wcf = (const float*)d_in[4];
    const float* Wco = (const float*)d_in[5];
    float* out = (float*)d_out;

    dim3 grid(8, 32, 4);    // 8-row tiles, cout-pairs, batch
    convqrnn<<<grid, 512, 0, stream>>>(X, Wc, bc, Wci, Wcf, Wco, out);
}

// Round 12
// 409.209 us; speedup vs baseline: 3.1342x; 1.1008x over previous
//
#include <hip/hip_runtime.h>

#define TT     32
#define HW     4096             // 64*64
#define LROW   68               // 66 cols + 2 pad -> rows 16B-aligned
#define NROWS  10               // 8 output rows + 2 halo
#define LPLANE (NROWS * LROW)   // 680
#define SXSZ   (3 * LPLANE)     // 2040 floats per plane buffer
#define NSTG   (3 * NROWS * 66) // 1980 staged elements per plane
#define GBSZ   2048             // 4 gates * 512 px (one cout)

__device__ __forceinline__ float fsigmoid(float x) {
    return __builtin_amdgcn_rcpf(1.0f + __builtin_amdgcn_exp2f(x * -1.4426950408889634f));
}
__device__ __forceinline__ float ftanh(float x) {
    return 2.0f * __builtin_amdgcn_rcpf(1.0f + __builtin_amdgcn_exp2f(x * -2.8853900817779268f)) - 1.0f;
}
__device__ __forceinline__ float sgprf(float v) {
    return __uint_as_float(__builtin_amdgcn_readfirstlane(__float_as_uint(v)));
}

// 256 thr = 4 waves = 4 gates, ONE cout, 8x64 tile. Round-11 inner structure
// (4-row window reuse, SGPR weights, float2 exchange) at round-6 occupancy:
// LDS ~32.7KB -> 4 blocks/CU, 4-wave barriers. Spill-proof ingredients only.
__global__ __launch_bounds__(256, 2) void convqrnn(
    const float* __restrict__ X,    // (4,3,32,64,64)
    const float* __restrict__ Wc,   // (256,3,2,3,3)
    const float* __restrict__ bc,   // (256)
    const float* __restrict__ Wci,  // (64,64,64)
    const float* __restrict__ Wcf,
    const float* __restrict__ Wco,
    float* __restrict__ out)        // (4,64,32,64,64)
{
    __shared__ float sx[2 * SXSZ];  // 16320 B staged planes (double-buffered)
    __shared__ float gb[2 * GBSZ];  // 16384 B gate exchange (double-buffered)

    const int tid = threadIdx.x;
    const int h0  = blockIdx.x * 8;    // 8 row-tiles of height 8
    const int co  = blockIdx.y;        // one cout per block
    const int b   = blockIdx.z;

    // gate-compute mapping: wave = gate g; lane owns 2 rows x 4 cols
    const int g  = tid >> 6;
    const int l  = tid & 63;
    const int r2 = l >> 4;             // row-pair 0..3 -> rows 2r2, 2r2+1
    const int c0 = (l & 15) * 4;       // col base

    // conv weights for (g, co): 54 floats -> SGPRs (proven no-spill pattern)
    float wgt[54];
    {
        const float* __restrict__ wrow = Wc + (size_t)(g * 64 + co) * 54;
        #pragma unroll
        for (int j = 0; j < 54; ++j) wgt[j] = sgprf(wrow[j]);
    }
    const float bg = sgprf(bc[g * 64 + co]);

    // recurrence-owner mapping: thread owns 2 consecutive px of this cout
    const int p2 = tid * 2;            // pixel pair within 8x64 tile
    const int ppix = co * HW + h0 * 64 + p2;
    const float2 pwci = *(const float2*)&Wci[ppix];
    const float2 pwcf = *(const float2*)&Wcf[ppix];
    const float2 pwco = *(const float2*)&Wco[ppix];
    float* __restrict__ outp =
        out + (size_t)(b * 64 + co) * (TT * HW) + h0 * 64 + p2;

    // ---- staging precompute: 8 chunks of 256 covering 3x10x66 halo tile ----
    const float* __restrict__ Xb = X + (size_t)b * (3 * TT * HW);
    int soff[8];
    int goff[8];
    int svmask = 0;
    #pragma unroll
    for (int k = 0; k < 8; ++k) {
        int idx  = tid + k * 256;
        bool inr = (idx < NSTG);
        int idc  = inr ? idx : 0;
        int ci   = idc / 660;              // 10*66
        int rem  = idc - ci * 660;
        int y    = rem / 66;
        int x    = rem - y * 66;
        int gh   = h0 + y - 1;
        int gw   = x - 1;
        bool v   = inr && (gh >= 0) && (gh < 64) && (gw >= 0) && (gw < 64);
        int ghc  = gh < 0 ? 0 : (gh > 63 ? 63 : gh);
        int gwc  = gw < 0 ? 0 : (gw > 63 ? 63 : gw);
        soff[k]  = inr ? (ci * LPLANE + y * LROW + x) : 66;  // 66 = pad slot
        goff[k]  = ci * (TT * HW) + ghc * 64 + gwc;          // plane 0
        svmask  |= (v ? 1 : 0) << k;
    }

    // prologue: stage plane t=0 into buffer 0
    #pragma unroll
    for (int k = 0; k < 8; ++k) {
        float v = ((svmask >> k) & 1) ? Xb[goff[k]] : 0.0f;
        sx[soff[k]] = v;
        goff[k] += HW;
    }

    // dt0 carries (named scalars) and cell state
    float na0 = 0.f, na1 = 0.f, na2 = 0.f, na3 = 0.f;   // row 2r2
    float nb0 = 0.f, nb1 = 0.f, nb2 = 0.f, nb3 = 0.f;   // row 2r2+1
    float Cc0 = 0.f, Cc1 = 0.f;

    __syncthreads();   // plane 0 staged

    for (int t = 0; t < TT; ++t) {
        const float* __restrict__ sxb = &sx[(t & 1) * SXSZ];
        float*       __restrict__ gbb = &gb[(t & 1) * GBSZ];

        // s init = bias + carry; reset carries
        float sa0 = bg + na0, sa1 = bg + na1, sa2 = bg + na2, sa3 = bg + na3;
        float sb0 = bg + nb0, sb1 = bg + nb1, sb2 = bg + nb2, sb3 = bg + nb3;
        na0 = na1 = na2 = na3 = 0.f;
        nb0 = nb1 = nb2 = nb3 = 0.f;

        // prefetch next plane's staging values (VMEM overlaps FMAs)
        float stv[8];
        if (t < TT - 1) {                    // uniform branch
            #pragma unroll
            for (int k = 0; k < 8; ++k) {
                stv[k] = ((svmask >> k) & 1) ? Xb[goff[k]] : 0.0f;
                goff[k] += HW;
            }
        }

        // conv: per ci read 4 window rows ONCE (12 LDS ops), reuse across kh
        #pragma unroll
        for (int ci = 0; ci < 3; ++ci) {
            float wv[4][6];
            #pragma unroll
            for (int j = 0; j < 4; ++j) {
                const float* rowp = &sxb[ci * LPLANE + (2 * r2 + j) * LROW + c0];
                float4 lo = *(const float4*)rowp;       // 16B aligned
                float2 hi = *(const float2*)(rowp + 4);
                wv[j][0] = lo.x; wv[j][1] = lo.y; wv[j][2] = lo.z;
                wv[j][3] = lo.w; wv[j][4] = hi.x; wv[j][5] = hi.y;
            }
            #pragma unroll
            for (int kh = 0; kh < 3; ++kh)
                #pragma unroll
                for (int kw = 0; kw < 3; ++kw) {
                    const float wp = wgt[ci * 18 +     kh * 3 + kw];
                    const float wc = wgt[ci * 18 + 9 + kh * 3 + kw];
                    sa0 += wc * wv[kh    ][kw + 0];  sa1 += wc * wv[kh    ][kw + 1];
                    sa2 += wc * wv[kh    ][kw + 2];  sa3 += wc * wv[kh    ][kw + 3];
                    sb0 += wc * wv[kh + 1][kw + 0];  sb1 += wc * wv[kh + 1][kw + 1];
                    sb2 += wc * wv[kh + 1][kw + 2];  sb3 += wc * wv[kh + 1][kw + 3];
                    na0 += wp * wv[kh    ][kw + 0];  na1 += wp * wv[kh    ][kw + 1];
                    na2 += wp * wv[kh    ][kw + 2];  na3 += wp * wv[kh    ][kw + 3];
                    nb0 += wp * wv[kh + 1][kw + 0];  nb1 += wp * wv[kh + 1][kw + 1];
                    nb2 += wp * wv[kh + 1][kw + 2];  nb3 += wp * wv[kh + 1][kw + 3];
                }
        }

        // gate exchange: 2 b128 writes (both rows)
        const int gbase = g * 512 + (2 * r2) * 64 + c0;
        *(float4*)&gbb[gbase]      = make_float4(sa0, sa1, sa2, sa3);
        *(float4*)&gbb[gbase + 64] = make_float4(sb0, sb1, sb2, sb3);

        // commit staged plane t+1 into the other buffer
        if (t < TT - 1) {                    // uniform branch
            float* __restrict__ sxn = &sx[((t + 1) & 1) * SXSZ];
            #pragma unroll
            for (int k = 0; k < 8; ++k) sxn[soff[k]] = stv[k];
        }

        __syncthreads();   // gates(t) + plane t+1 visible

        // recurrence: owner thread, 2 pixels (4x b64 gate reads)
        {
            const float2 iv = *(const float2*)&gbb[p2];
            const float2 fv = *(const float2*)&gbb[512 + p2];
            const float2 gv = *(const float2*)&gbb[1024 + p2];
            const float2 ov = *(const float2*)&gbb[1536 + p2];
            float o0, o1;
            {
                const float ig = fsigmoid(iv.x + pwci.x * Cc0);
                const float fg = fsigmoid(fv.x + pwcf.x * Cc0);
                const float Cn = fg * Cc0 + ig * ftanh(gv.x);
                const float og = fsigmoid(ov.x + pwco.x * Cn);
                o0 = og * ftanh(Cn);  Cc0 = Cn;
            }
            {
                const float ig = fsigmoid(iv.y + pwci.y * Cc1);
                const float fg = fsigmoid(fv.y + pwcf.y * Cc1);
                const float Cn = fg * Cc1 + ig * ftanh(gv.y);
                const float og = fsigmoid(ov.y + pwco.y * Cn);
                o1 = og * ftanh(Cn);  Cc1 = Cn;
            }
            *(float2*)&outp[t * HW] = make_float2(o0, o1);
        }
    }
}

extern "C" void kernel_launch(void* const* d_in, const int* in_sizes, int n_in,
                              void* d_out, int out_size, void* d_ws, size_t ws_size,
                              hipStream_t stream) {
    const float* X   = (const float*)d_in[0];
    const float* Wc  = (const float*)d_in[1];
    const float* bc  = (const float*)d_in[2];
    const float* Wci = (const float*)d_in[3];
    const float* Wcf = (const float*)d_in[4];
    const float* Wco = (const float*)d_in[5];
    float* out = (float*)d_out;

    dim3 grid(8, 64, 4);    // 8-row tiles, couts, batch
    convqrnn<<<grid, 256, 0, stream>>>(X, Wc, bc, Wci, Wcf, Wco, out);
}